// Round 12
// baseline (738.609 us; speedup 1.0000x reference)
//
#include <hip/hip_runtime.h>

// ---------------------------------------------------------------------------
// LIIF-style MLP render on MI355X — R12.
//  R10 verbatim (1024 thr / 16 waves / ROWS=256 / 64x64 tiles / acc[4][4] /
//  1 block/CU / direct-global B / PI packed writeback / per-row-group sync)
//  + two pure-schedule changes: s_setprio(1/0) around each panel's 16-MFMA
//  cluster (group drift gives the CU scheduler role-diverse waves), and the
//  panel loop fully unrolled (compile-time kp -> scheduler pipelines loads
//  itself within the register budget; no named buffers -> no R11 spill).
//  Numerics verbatim R10 -> output bit-identical.
// ---------------------------------------------------------------------------

typedef _Float16 half8 __attribute__((ext_vector_type(8)));
typedef float f32x4 __attribute__((ext_vector_type(4)));

#define ROWS     256          // rows per block (query-shift pairs)
#define THREADS  1024

#define A_BYTES    131072     // 256 rows x 512 B (256 k x fp16)
#define AREA_OFF   131072     // 256 x f32
#define PRED_OFF   132096     // 256 x 4 x f32
#define FLAG_OFF   136192     // 8 x int (4 rflag + 4 wflag)
#define SMEM_BYTES 136224     // 133 KB -> 1 block/CU

static __device__ __forceinline__ unsigned short f2h(float f) {
    union { _Float16 h; unsigned short u; } v;
    v.h = (_Float16)f;   // v_cvt_f16_f32, RNE
    return v.u;
}

// swizzle: XOR 16B-slot index with row&7 (keeps 16B alignment, bijective)
#define SWZ(row, byte) ((byte) ^ (((row) & 7) << 4))

// column permutation: physical MFMA col p -> logical col PI(p).
// p = wn*64 + cf*16 + l15  ->  wn*64 + l15*4 + cf   (bijective per 64-block)
static __device__ __host__ __forceinline__ int PI(int p) {
    return ((p >> 6) << 6) | ((p & 15) << 2) | ((p >> 4) & 3);
}

// ---------------------------------------------------------------------------
// feat [B][C][H][W] f32  ->  featT [B][H][W][C] fp16  (LDS tile transpose)
// ---------------------------------------------------------------------------
__global__ void transpose_feat(const float* __restrict__ feat,
                               unsigned short* __restrict__ featT) {
    __shared__ float tile[64][65];
    const int bi  = blockIdx.x;          // B*H*2 = 1024 blocks
    const int b   = bi >> 8;
    const int rem = bi & 255;
    const int y   = rem >> 1;
    const int xc  = (rem & 1) << 6;
    const int tid = threadIdx.x;

    {
        const int x  = tid & 63;
        const int cg = tid >> 6;          // 0..3
#pragma unroll
        for (int i = 0; i < 16; ++i) {
            int c = cg * 16 + i;
            tile[c][x] = feat[(((b << 6) + c) << 14) + (y << 7) + xc + x];
        }
    }
    __syncthreads();
    {
        const int c  = tid & 63;
        const int xg = tid >> 6;
#pragma unroll
        for (int i = 0; i < 16; ++i) {
            int xx = xg * 16 + i;
            featT[(size_t)((((b << 7) + y) << 7) + xc + xx) * 64 + c] =
                f2h(tile[c][xx]);
        }
    }
}

// ---------------------------------------------------------------------------
// Pack weight [K][N] f32 -> fragment layout fp16:
//   dst[((ks*nct + ct)*64 + lane)*8 + j] = W[k][n_src],
//   k = ks*32 + (lane>>4)*8 + j, n_phys = ct*16 + (lane&15),
//   n_src = permN ? PI(n_phys) : n_phys.  Zero-padded outside K,N.
// ---------------------------------------------------------------------------
__global__ void pack_w(const float* __restrict__ src,
                       unsigned short* __restrict__ dst,
                       int K, int N, int ksteps, int nct, int permN) {
    int tid = blockIdx.x * 256 + threadIdx.x;
    int total = ksteps * nct * 512;
    if (tid >= total) return;
    int j    = tid & 7;
    int lane = (tid >> 3) & 63;
    int f    = tid >> 9;
    int ct   = f % nct;
    int ks   = f / nct;
    int k = ks * 32 + ((lane >> 4) << 3) + j;
    int n = ct * 16 + (lane & 15);
    int ns = permN ? PI(n) : n;
    float v = (k < K && ns < N) ? src[k * N + ns] : 0.0f;
    dst[tid] = f2h(v);
}

// ---------------------------------------------------------------------------
// One hidden layer: K-panel MFMA loop + PI writeback, group-scoped sync.
// ---------------------------------------------------------------------------
template <int NP>
static __device__ __forceinline__ void layer_step(
    char* A, int* rflag, int* wflag, int target,
    const unsigned short* __restrict__ wsel,
    const float* __restrict__ bsel,
    int lane, int wm, int wn) {

    const int l15 = lane & 15;
    f32x4 acc[4][4];
#pragma unroll
    for (int rf = 0; rf < 4; ++rf)
#pragma unroll
        for (int cf = 0; cf < 4; ++cf)
            acc[rf][cf] = (f32x4){0.f, 0.f, 0.f, 0.f};

#pragma unroll
    for (int kp = 0; kp < NP; ++kp) {
        half8 af[4];
        const int kbyte = (kp << 6) + ((lane >> 4) << 4);
        const int xorv  = (lane & 7) << 4;
#pragma unroll
        for (int rf = 0; rf < 4; ++rf) {
            int row = wm * 64 + rf * 16 + l15;
            af[rf] = *(const half8*)(A + row * 512 + (kbyte ^ xorv));
        }
        __builtin_amdgcn_s_setprio(1);
#pragma unroll
        for (int cf = 0; cf < 4; ++cf) {
            half8 bf = *(const half8*)(wsel + (size_t)((kp * 16 + wn * 4 + cf) * 64 + lane) * 8);
#pragma unroll
            for (int rf = 0; rf < 4; ++rf)
                acc[rf][cf] = __builtin_amdgcn_mfma_f32_16x16x32_f16(
                    af[rf], bf, acc[rf][cf], 0, 0, 0);
        }
        __builtin_amdgcn_s_setprio(0);
    }

    // group-scoped "all A reads done" (RELEASE drains lgkmcnt incl. reads)
    if (lane == 0)
        __hip_atomic_fetch_add(rflag, 1, __ATOMIC_RELEASE,
                               __HIP_MEMORY_SCOPE_WORKGROUP);
    while (__hip_atomic_load(rflag, __ATOMIC_ACQUIRE,
                             __HIP_MEMORY_SCOPE_WORKGROUP) < target)
        __builtin_amdgcn_s_sleep(1);

    // bias + relu + PACKED writeback (PI: thread's 4 cols contiguous)
    const float4 bias = *(const float4*)(bsel + wn * 64 + l15 * 4);
    const int colbyte = (wn << 7) + (l15 << 3);   // logical col * 2B

#pragma unroll
    for (int rf = 0; rf < 4; ++rf) {
        const int rbase = wm * 64 + rf * 16 + ((lane >> 4) << 2);
#pragma unroll
        for (int q = 0; q < 4; ++q) {
            const int row = rbase + q;
            union { _Float16 h[4]; uint2 u; } pk;
            pk.h[0] = (_Float16)fmaxf(acc[rf][0][q] + bias.x, 0.0f);
            pk.h[1] = (_Float16)fmaxf(acc[rf][1][q] + bias.y, 0.0f);
            pk.h[2] = (_Float16)fmaxf(acc[rf][2][q] + bias.z, 0.0f);
            pk.h[3] = (_Float16)fmaxf(acc[rf][3][q] + bias.w, 0.0f);
            *(uint2*)(A + row * 512 + (colbyte ^ ((row & 7) << 4))) = pk.u;
        }
    }

    // group-scoped "all A writes done" (RELEASE drains the ds_writes)
    if (lane == 0)
        __hip_atomic_fetch_add(wflag, 1, __ATOMIC_RELEASE,
                               __HIP_MEMORY_SCOPE_WORKGROUP);
    while (__hip_atomic_load(wflag, __ATOMIC_ACQUIRE,
                             __HIP_MEMORY_SCOPE_WORKGROUP) < target)
        __builtin_amdgcn_s_sleep(1);
}

// ---------------------------------------------------------------------------
// Main fused kernel
// ---------------------------------------------------------------------------
__global__ __launch_bounds__(1024, 4) void mlp_main(
    const unsigned short* __restrict__ featT,
    const float* __restrict__ sgrid,
    const float* __restrict__ scell,
    const unsigned short* __restrict__ wp0, const unsigned short* __restrict__ wp1,
    const unsigned short* __restrict__ wp2, const unsigned short* __restrict__ wp3,
    const unsigned short* __restrict__ wp4,
    const float* __restrict__ bp0, const float* __restrict__ bp1,
    const float* __restrict__ bp2, const float* __restrict__ bp3,
    const float* __restrict__ bp4,
    float* __restrict__ out) {

    extern __shared__ char lds[];
    char*  A     = lds;                          // 256 x 512B fp16 activations
    float* areas = (float*)(lds + AREA_OFF);     // 256 f32
    float* predl = (float*)(lds + PRED_OFF);     // 256 x 4 f32
    int*   flags = (int*)(lds + FLAG_OFF);       // [0..3]=rflag [4..7]=wflag

    const int tid  = threadIdx.x;
    const int lane = tid & 63;
    const int wv   = tid >> 6;     // wave 0..15
    const int wm   = wv >> 2;      // row quarter (0..3): rows wm*64..+63
    const int wn   = wv & 3;       // col quarter (0..3): cols wn*64..+63

    if (tid < 8) flags[tid] = 0;

    // ---------------- phase 0: build MLP inputs into A (R4/R6 verbatim) ----
    if (tid < 512) {
        const int row  = tid >> 1;
        const int half = tid & 1;
        const int grow = blockIdx.x * ROWS + row;
        const int qq   = grow >> 2;        // global query index (b*Q+q)
        const int s    = grow & 3;         // shift: 0:(-,-) 1:(-,+) 2:(+,-) 3:(+,+)
        const int b    = qq >> 16;

        const float g0 = sgrid[qq * 2 + 0];
        const float g1 = sgrid[qq * 2 + 1];
        const float c0 = scell[qq * 2 + 0];
        const float c1 = scell[qq * 2 + 1];

        const float rs = (s & 2) ? 1.0f : -1.0f;
        const float cs = (s & 1) ? 1.0f : -1.0f;
        const float dh = 0.0078125f;                   // 1/128
        const float LO = (float)(-1.0 + 1e-6);
        const float HI = (float)( 1.0 - 1e-6);

        // exact same fp32 op order as reference
        float gy = fminf(fmaxf(g0 + rs * dh, LO), HI);
        float gx = fminf(fmaxf(g1 + cs * dh, LO), HI);
        float ty = ((gy + 1.0f) * 128.0f - 1.0f) * 0.5f;
        float tx = ((gx + 1.0f) * 128.0f - 1.0f) * 0.5f;
        int iy = (int)rintf(ty); iy = min(max(iy, 0), 127);
        int ix = (int)rintf(tx); ix = min(max(ix, 0), 127);

        float py = -1.0f + (float)(2 * iy + 1) * 0.0078125f;
        float px = -1.0f + (float)(2 * ix + 1) * 0.0078125f;
        float rel_y = (g0 - py) * 128.0f;
        float rel_x = (g1 - px) * 128.0f;
        float qcy = c0 * 128.0f;
        float qcx = c1 * 128.0f;

        if (half == 0) areas[row] = fabsf(rel_y * rel_x) + 1e-9f;

        // gather 32 channels (64B) of fp16 features
        const unsigned short* src =
            featT + (size_t)((((b << 7) + iy) << 7) + ix) * 64 + (half << 5);
        uint4 v0 = *(const uint4*)(src + 0);
        uint4 v1 = *(const uint4*)(src + 8);
        uint4 v2 = *(const uint4*)(src + 16);
        uint4 v3 = *(const uint4*)(src + 24);

        char* arow = A + row * 512;
        const int kb0 = half << 6;     // byte offset of k = half*32
        *(uint4*)(arow + SWZ(row, kb0 +  0)) = v0;
        *(uint4*)(arow + SWZ(row, kb0 + 16)) = v1;
        *(uint4*)(arow + SWZ(row, kb0 + 32)) = v2;
        *(uint4*)(arow + SWZ(row, kb0 + 48)) = v3;

        if (half) {    // k = 64..95 : rel_y, rel_x, qcy, qcx, zeros
            uint4 t;
            t.x = (unsigned)f2h(rel_y) | ((unsigned)f2h(rel_x) << 16);
            t.y = (unsigned)f2h(qcy)   | ((unsigned)f2h(qcx)   << 16);
            t.z = 0; t.w = 0;
            uint4 z = {0, 0, 0, 0};
            *(uint4*)(arow + SWZ(row, 128)) = t;
            *(uint4*)(arow + SWZ(row, 144)) = z;
            *(uint4*)(arow + SWZ(row, 160)) = z;
            *(uint4*)(arow + SWZ(row, 176)) = z;
        }
    }
    __syncthreads();   // phase 0 + flag init visible to all (cross-group)

    // ---------------- layers 0..3 (group-scoped sync) ----------------
    int* rflag = &flags[wm];
    int* wflag = &flags[4 + wm];
    layer_step<3>(A, rflag, wflag,  4, wp0, bp0, lane, wm, wn);
    layer_step<8>(A, rflag, wflag,  8, wp1, bp1, lane, wm, wn);
    layer_step<8>(A, rflag, wflag, 12, wp2, bp2, lane, wm, wn);
    layer_step<8>(A, rflag, wflag, 16, wp3, bp3, lane, wm, wn);

    // ---------------- layer 4 (256 -> 3, N padded to 16) -------------------
    // wave wv reads rows wv*16..+15, all inside its own group wm=wv>>2,
    // whose final writes are guaranteed by the last wflag spin above.
    {
        f32x4 a4 = (f32x4){0.f, 0.f, 0.f, 0.f};
        const int xorv = (lane & 7) << 4;
#pragma unroll
        for (int kp = 0; kp < 8; ++kp) {
            const int kbyte = (kp << 6) + ((lane >> 4) << 4);
            half8 b = *(const half8*)(wp4 + (size_t)((kp * 64) + lane) * 8);
            int row = wv * 16 + (lane & 15);
            half8 a = *(const half8*)(A + row * 512 + (kbyte ^ xorv));
            a4 = __builtin_amdgcn_mfma_f32_16x16x32_f16(a, b, a4, 0, 0, 0);
        }

        const int col = lane & 15;
        const float b4v = (col < 3) ? bp4[col] : 0.0f;
        if (col < 3) {
#pragma unroll
            for (int q = 0; q < 4; ++q) {
                int row = wv * 16 + ((lane >> 4) << 2) + q;
                predl[row * 4 + col] = a4[q] + b4v;
            }
        }
        __syncthreads();   // predl is read cross-group below

        // combine 4 shifts with diagonally swapped areas (R6 verbatim)
        if (tid < 192) {
            int qloc = tid / 3;
            int c    = tid - qloc * 3;
            int r0   = qloc * 4;
            float a0 = areas[r0 + 0], a1 = areas[r0 + 1];
            float a2 = areas[r0 + 2], a3 = areas[r0 + 3];
            float total = ((a0 + a1) + a2) + a3;
            float ret = predl[(r0 + 0) * 4 + c] * (a3 / total);
            ret      += predl[(r0 + 1) * 4 + c] * (a2 / total);
            ret      += predl[(r0 + 2) * 4 + c] * (a1 / total);
            ret      += predl[(r0 + 3) * 4 + c] * (a0 / total);
            int qq0 = blockIdx.x * 64 + qloc;
            out[qq0 * 3 + c] = ret;
        }
    }
}

// ---------------------------------------------------------------------------
extern "C" void kernel_launch(void* const* d_in, const int* in_sizes, int n_in,
                              void* d_out, int out_size, void* d_ws, size_t ws_size,
                              hipStream_t stream) {
    const float* feat  = (const float*)d_in[0];
    const float* sgrid = (const float*)d_in[1];
    const float* scell = (const float*)d_in[2];
    const float* w0 = (const float*)d_in[3];
    const float* b0 = (const float*)d_in[4];
    const float* w1 = (const float*)d_in[5];
    const float* b1 = (const float*)d_in[6];
    const float* w2 = (const float*)d_in[7];
    const float* b2 = (const float*)d_in[8];
    const float* w3 = (const float*)d_in[9];
    const float* b3 = (const float*)d_in[10];
    const float* w4 = (const float*)d_in[11];
    const float* b4 = (const float*)d_in[12];

    char* ws = (char*)d_ws;
    unsigned short* featT = (unsigned short*)ws;
    unsigned short* wp0 = (unsigned short*)(ws + 8388608);
    unsigned short* wp1 = (unsigned short*)(ws + 8388608 + 49152);
    unsigned short* wp2 = (unsigned short*)(ws + 8388608 + 49152 + 131072);
    unsigned short* wp3 = (unsigned short*)(ws + 8388608 + 49152 + 2 * 131072);
    unsigned short* wp4 = (unsigned short*)(ws + 8388608 + 49152 + 3 * 131072);

    transpose_feat<<<1024, 256, 0, stream>>>(feat, featT);
    pack_w<<<96,  256, 0, stream>>>(w0, wp0,  68, 256, 3, 16, 1);
    pack_w<<<256, 256, 0, stream>>>(w1, wp1, 256, 256, 8, 16, 1);
    pack_w<<<256, 256, 0, stream>>>(w2, wp2, 256, 256, 8, 16, 1);
    pack_w<<<256, 256, 0, stream>>>(w3, wp3, 256, 256, 8, 16, 1);
    pack_w<<<16,  256, 0, stream>>>(w4, wp4, 256, 3, 8, 1, 0);

    hipFuncSetAttribute(reinterpret_cast<const void*>(mlp_main),
                        hipFuncAttributeMaxDynamicSharedMemorySize, SMEM_BYTES);
    mlp_main<<<4096, THREADS, SMEM_BYTES, stream>>>(
        featT, sgrid, scell, wp0, wp1, wp2, wp3, wp4,
        b0, b1, b2, b3, b4, (float*)d_out);
}

// Round 13
// 448.041 us; speedup vs baseline: 1.6485x; 1.6485x over previous
//
#include <hip/hip_runtime.h>

// ---------------------------------------------------------------------------
// LIIF-style MLP render on MI355X — R13.
//  R10 verbatim (1024 thr / 16 waves / ROWS=256 / 64x64 tiles / acc[4][4] /
//  1 block/CU / direct-global B / PI packed writeback / per-row-group sync /
//  #pragma unroll 2 on panel loop — the widest non-spilling unroll).
//  Single change-cluster: spin-pollution mitigation — s_setprio(1/0) around
//  each panel's 16-MFMA cluster (scheduler prefers working waves over
//  spinners) and s_sleep(4) in the spin loops (fewer poll issues).
//  Zero register cost, zero load reordering -> output bit-identical to R10.
// ---------------------------------------------------------------------------

typedef _Float16 half8 __attribute__((ext_vector_type(8)));
typedef float f32x4 __attribute__((ext_vector_type(4)));

#define ROWS     256          // rows per block (query-shift pairs)
#define THREADS  1024

#define A_BYTES    131072     // 256 rows x 512 B (256 k x fp16)
#define AREA_OFF   131072     // 256 x f32
#define PRED_OFF   132096     // 256 x 4 x f32
#define FLAG_OFF   136192     // 8 x int (4 rflag + 4 wflag)
#define SMEM_BYTES 136224     // 133 KB -> 1 block/CU

static __device__ __forceinline__ unsigned short f2h(float f) {
    union { _Float16 h; unsigned short u; } v;
    v.h = (_Float16)f;   // v_cvt_f16_f32, RNE
    return v.u;
}

// swizzle: XOR 16B-slot index with row&7 (keeps 16B alignment, bijective)
#define SWZ(row, byte) ((byte) ^ (((row) & 7) << 4))

// column permutation: physical MFMA col p -> logical col PI(p).
// p = wn*64 + cf*16 + l15  ->  wn*64 + l15*4 + cf   (bijective per 64-block)
static __device__ __host__ __forceinline__ int PI(int p) {
    return ((p >> 6) << 6) | ((p & 15) << 2) | ((p >> 4) & 3);
}

// ---------------------------------------------------------------------------
// feat [B][C][H][W] f32  ->  featT [B][H][W][C] fp16  (LDS tile transpose)
// ---------------------------------------------------------------------------
__global__ void transpose_feat(const float* __restrict__ feat,
                               unsigned short* __restrict__ featT) {
    __shared__ float tile[64][65];
    const int bi  = blockIdx.x;          // B*H*2 = 1024 blocks
    const int b   = bi >> 8;
    const int rem = bi & 255;
    const int y   = rem >> 1;
    const int xc  = (rem & 1) << 6;
    const int tid = threadIdx.x;

    {
        const int x  = tid & 63;
        const int cg = tid >> 6;          // 0..3
#pragma unroll
        for (int i = 0; i < 16; ++i) {
            int c = cg * 16 + i;
            tile[c][x] = feat[(((b << 6) + c) << 14) + (y << 7) + xc + x];
        }
    }
    __syncthreads();
    {
        const int c  = tid & 63;
        const int xg = tid >> 6;
#pragma unroll
        for (int i = 0; i < 16; ++i) {
            int xx = xg * 16 + i;
            featT[(size_t)((((b << 7) + y) << 7) + xc + xx) * 64 + c] =
                f2h(tile[c][xx]);
        }
    }
}

// ---------------------------------------------------------------------------
// Pack weight [K][N] f32 -> fragment layout fp16:
//   dst[((ks*nct + ct)*64 + lane)*8 + j] = W[k][n_src],
//   k = ks*32 + (lane>>4)*8 + j, n_phys = ct*16 + (lane&15),
//   n_src = permN ? PI(n_phys) : n_phys.  Zero-padded outside K,N.
// ---------------------------------------------------------------------------
__global__ void pack_w(const float* __restrict__ src,
                       unsigned short* __restrict__ dst,
                       int K, int N, int ksteps, int nct, int permN) {
    int tid = blockIdx.x * 256 + threadIdx.x;
    int total = ksteps * nct * 512;
    if (tid >= total) return;
    int j    = tid & 7;
    int lane = (tid >> 3) & 63;
    int f    = tid >> 9;
    int ct   = f % nct;
    int ks   = f / nct;
    int k = ks * 32 + ((lane >> 4) << 3) + j;
    int n = ct * 16 + (lane & 15);
    int ns = permN ? PI(n) : n;
    float v = (k < K && ns < N) ? src[k * N + ns] : 0.0f;
    dst[tid] = f2h(v);
}

// ---------------------------------------------------------------------------
// One hidden layer: K-panel MFMA loop + PI writeback, group-scoped sync.
// ---------------------------------------------------------------------------
template <int NP>
static __device__ __forceinline__ void layer_step(
    char* A, int* rflag, int* wflag, int target,
    const unsigned short* __restrict__ wsel,
    const float* __restrict__ bsel,
    int lane, int wm, int wn) {

    const int l15 = lane & 15;
    f32x4 acc[4][4];
#pragma unroll
    for (int rf = 0; rf < 4; ++rf)
#pragma unroll
        for (int cf = 0; cf < 4; ++cf)
            acc[rf][cf] = (f32x4){0.f, 0.f, 0.f, 0.f};

#pragma unroll 2
    for (int kp = 0; kp < NP; ++kp) {
        half8 af[4], bf[4];
        const int kbyte = (kp << 6) + ((lane >> 4) << 4);
        const int xorv  = (lane & 7) << 4;
#pragma unroll
        for (int rf = 0; rf < 4; ++rf) {
            int row = wm * 64 + rf * 16 + l15;
            af[rf] = *(const half8*)(A + row * 512 + (kbyte ^ xorv));
        }
#pragma unroll
        for (int cf = 0; cf < 4; ++cf)
            bf[cf] = *(const half8*)(wsel + (size_t)((kp * 16 + wn * 4 + cf) * 64 + lane) * 8);
        __builtin_amdgcn_s_setprio(1);
#pragma unroll
        for (int rf = 0; rf < 4; ++rf)
#pragma unroll
            for (int cf = 0; cf < 4; ++cf)
                acc[rf][cf] = __builtin_amdgcn_mfma_f32_16x16x32_f16(
                    af[rf], bf[cf], acc[rf][cf], 0, 0, 0);
        __builtin_amdgcn_s_setprio(0);
    }

    // group-scoped "all A reads done" (RELEASE drains lgkmcnt incl. reads)
    if (lane == 0)
        __hip_atomic_fetch_add(rflag, 1, __ATOMIC_RELEASE,
                               __HIP_MEMORY_SCOPE_WORKGROUP);
    while (__hip_atomic_load(rflag, __ATOMIC_ACQUIRE,
                             __HIP_MEMORY_SCOPE_WORKGROUP) < target)
        __builtin_amdgcn_s_sleep(4);

    // bias + relu + PACKED writeback (PI: thread's 4 cols contiguous)
    const float4 bias = *(const float4*)(bsel + wn * 64 + l15 * 4);
    const int colbyte = (wn << 7) + (l15 << 3);   // logical col * 2B

#pragma unroll
    for (int rf = 0; rf < 4; ++rf) {
        const int rbase = wm * 64 + rf * 16 + ((lane >> 4) << 2);
#pragma unroll
        for (int q = 0; q < 4; ++q) {
            const int row = rbase + q;
            union { _Float16 h[4]; uint2 u; } pk;
            pk.h[0] = (_Float16)fmaxf(acc[rf][0][q] + bias.x, 0.0f);
            pk.h[1] = (_Float16)fmaxf(acc[rf][1][q] + bias.y, 0.0f);
            pk.h[2] = (_Float16)fmaxf(acc[rf][2][q] + bias.z, 0.0f);
            pk.h[3] = (_Float16)fmaxf(acc[rf][3][q] + bias.w, 0.0f);
            *(uint2*)(A + row * 512 + (colbyte ^ ((row & 7) << 4))) = pk.u;
        }
    }

    // group-scoped "all A writes done" (RELEASE drains the ds_writes)
    if (lane == 0)
        __hip_atomic_fetch_add(wflag, 1, __ATOMIC_RELEASE,
                               __HIP_MEMORY_SCOPE_WORKGROUP);
    while (__hip_atomic_load(wflag, __ATOMIC_ACQUIRE,
                             __HIP_MEMORY_SCOPE_WORKGROUP) < target)
        __builtin_amdgcn_s_sleep(4);
}

// ---------------------------------------------------------------------------
// Main fused kernel
// ---------------------------------------------------------------------------
__global__ __launch_bounds__(1024, 4) void mlp_main(
    const unsigned short* __restrict__ featT,
    const float* __restrict__ sgrid,
    const float* __restrict__ scell,
    const unsigned short* __restrict__ wp0, const unsigned short* __restrict__ wp1,
    const unsigned short* __restrict__ wp2, const unsigned short* __restrict__ wp3,
    const unsigned short* __restrict__ wp4,
    const float* __restrict__ bp0, const float* __restrict__ bp1,
    const float* __restrict__ bp2, const float* __restrict__ bp3,
    const float* __restrict__ bp4,
    float* __restrict__ out) {

    extern __shared__ char lds[];
    char*  A     = lds;                          // 256 x 512B fp16 activations
    float* areas = (float*)(lds + AREA_OFF);     // 256 f32
    float* predl = (float*)(lds + PRED_OFF);     // 256 x 4 f32
    int*   flags = (int*)(lds + FLAG_OFF);       // [0..3]=rflag [4..7]=wflag

    const int tid  = threadIdx.x;
    const int lane = tid & 63;
    const int wv   = tid >> 6;     // wave 0..15
    const int wm   = wv >> 2;      // row quarter (0..3): rows wm*64..+63
    const int wn   = wv & 3;       // col quarter (0..3): cols wn*64..+63

    if (tid < 8) flags[tid] = 0;

    // ---------------- phase 0: build MLP inputs into A (R4/R6 verbatim) ----
    if (tid < 512) {
        const int row  = tid >> 1;
        const int half = tid & 1;
        const int grow = blockIdx.x * ROWS + row;
        const int qq   = grow >> 2;        // global query index (b*Q+q)
        const int s    = grow & 3;         // shift: 0:(-,-) 1:(-,+) 2:(+,-) 3:(+,+)
        const int b    = qq >> 16;

        const float g0 = sgrid[qq * 2 + 0];
        const float g1 = sgrid[qq * 2 + 1];
        const float c0 = scell[qq * 2 + 0];
        const float c1 = scell[qq * 2 + 1];

        const float rs = (s & 2) ? 1.0f : -1.0f;
        const float cs = (s & 1) ? 1.0f : -1.0f;
        const float dh = 0.0078125f;                   // 1/128
        const float LO = (float)(-1.0 + 1e-6);
        const float HI = (float)( 1.0 - 1e-6);

        // exact same fp32 op order as reference
        float gy = fminf(fmaxf(g0 + rs * dh, LO), HI);
        float gx = fminf(fmaxf(g1 + cs * dh, LO), HI);
        float ty = ((gy + 1.0f) * 128.0f - 1.0f) * 0.5f;
        float tx = ((gx + 1.0f) * 128.0f - 1.0f) * 0.5f;
        int iy = (int)rintf(ty); iy = min(max(iy, 0), 127);
        int ix = (int)rintf(tx); ix = min(max(ix, 0), 127);

        float py = -1.0f + (float)(2 * iy + 1) * 0.0078125f;
        float px = -1.0f + (float)(2 * ix + 1) * 0.0078125f;
        float rel_y = (g0 - py) * 128.0f;
        float rel_x = (g1 - px) * 128.0f;
        float qcy = c0 * 128.0f;
        float qcx = c1 * 128.0f;

        if (half == 0) areas[row] = fabsf(rel_y * rel_x) + 1e-9f;

        // gather 32 channels (64B) of fp16 features
        const unsigned short* src =
            featT + (size_t)((((b << 7) + iy) << 7) + ix) * 64 + (half << 5);
        uint4 v0 = *(const uint4*)(src + 0);
        uint4 v1 = *(const uint4*)(src + 8);
        uint4 v2 = *(const uint4*)(src + 16);
        uint4 v3 = *(const uint4*)(src + 24);

        char* arow = A + row * 512;
        const int kb0 = half << 6;     // byte offset of k = half*32
        *(uint4*)(arow + SWZ(row, kb0 +  0)) = v0;
        *(uint4*)(arow + SWZ(row, kb0 + 16)) = v1;
        *(uint4*)(arow + SWZ(row, kb0 + 32)) = v2;
        *(uint4*)(arow + SWZ(row, kb0 + 48)) = v3;

        if (half) {    // k = 64..95 : rel_y, rel_x, qcy, qcx, zeros
            uint4 t;
            t.x = (unsigned)f2h(rel_y) | ((unsigned)f2h(rel_x) << 16);
            t.y = (unsigned)f2h(qcy)   | ((unsigned)f2h(qcx)   << 16);
            t.z = 0; t.w = 0;
            uint4 z = {0, 0, 0, 0};
            *(uint4*)(arow + SWZ(row, 128)) = t;
            *(uint4*)(arow + SWZ(row, 144)) = z;
            *(uint4*)(arow + SWZ(row, 160)) = z;
            *(uint4*)(arow + SWZ(row, 176)) = z;
        }
    }
    __syncthreads();   // phase 0 + flag init visible to all (cross-group)

    // ---------------- layers 0..3 (group-scoped sync) ----------------
    int* rflag = &flags[wm];
    int* wflag = &flags[4 + wm];
    layer_step<3>(A, rflag, wflag,  4, wp0, bp0, lane, wm, wn);
    layer_step<8>(A, rflag, wflag,  8, wp1, bp1, lane, wm, wn);
    layer_step<8>(A, rflag, wflag, 12, wp2, bp2, lane, wm, wn);
    layer_step<8>(A, rflag, wflag, 16, wp3, bp3, lane, wm, wn);

    // ---------------- layer 4 (256 -> 3, N padded to 16) -------------------
    // wave wv reads rows wv*16..+15, all inside its own group wm=wv>>2,
    // whose final writes are guaranteed by the last wflag spin above.
    {
        f32x4 a4 = (f32x4){0.f, 0.f, 0.f, 0.f};
        const int xorv = (lane & 7) << 4;
#pragma unroll
        for (int kp = 0; kp < 8; ++kp) {
            const int kbyte = (kp << 6) + ((lane >> 4) << 4);
            half8 b = *(const half8*)(wp4 + (size_t)((kp * 64) + lane) * 8);
            int row = wv * 16 + (lane & 15);
            half8 a = *(const half8*)(A + row * 512 + (kbyte ^ xorv));
            a4 = __builtin_amdgcn_mfma_f32_16x16x32_f16(a, b, a4, 0, 0, 0);
        }

        const int col = lane & 15;
        const float b4v = (col < 3) ? bp4[col] : 0.0f;
        if (col < 3) {
#pragma unroll
            for (int q = 0; q < 4; ++q) {
                int row = wv * 16 + ((lane >> 4) << 2) + q;
                predl[row * 4 + col] = a4[q] + b4v;
            }
        }
        __syncthreads();   // predl is read cross-group below

        // combine 4 shifts with diagonally swapped areas (R6 verbatim)
        if (tid < 192) {
            int qloc = tid / 3;
            int c    = tid - qloc * 3;
            int r0   = qloc * 4;
            float a0 = areas[r0 + 0], a1 = areas[r0 + 1];
            float a2 = areas[r0 + 2], a3 = areas[r0 + 3];
            float total = ((a0 + a1) + a2) + a3;
            float ret = predl[(r0 + 0) * 4 + c] * (a3 / total);
            ret      += predl[(r0 + 1) * 4 + c] * (a2 / total);
            ret      += predl[(r0 + 2) * 4 + c] * (a1 / total);
            ret      += predl[(r0 + 3) * 4 + c] * (a0 / total);
            int qq0 = blockIdx.x * 64 + qloc;
            out[qq0 * 3 + c] = ret;
        }
    }
}

// ---------------------------------------------------------------------------
extern "C" void kernel_launch(void* const* d_in, const int* in_sizes, int n_in,
                              void* d_out, int out_size, void* d_ws, size_t ws_size,
                              hipStream_t stream) {
    const float* feat  = (const float*)d_in[0];
    const float* sgrid = (const float*)d_in[1];
    const float* scell = (const float*)d_in[2];
    const float* w0 = (const float*)d_in[3];
    const float* b0 = (const float*)d_in[4];
    const float* w1 = (const float*)d_in[5];
    const float* b1 = (const float*)d_in[6];
    const float* w2 = (const float*)d_in[7];
    const float* b2 = (const float*)d_in[8];
    const float* w3 = (const float*)d_in[9];
    const float* b3 = (const float*)d_in[10];
    const float* w4 = (const float*)d_in[11];
    const float* b4 = (const float*)d_in[12];

    char* ws = (char*)d_ws;
    unsigned short* featT = (unsigned short*)ws;
    unsigned short* wp0 = (unsigned short*)(ws + 8388608);
    unsigned short* wp1 = (unsigned short*)(ws + 8388608 + 49152);
    unsigned short* wp2 = (unsigned short*)(ws + 8388608 + 49152 + 131072);
    unsigned short* wp3 = (unsigned short*)(ws + 8388608 + 49152 + 2 * 131072);
    unsigned short* wp4 = (unsigned short*)(ws + 8388608 + 49152 + 3 * 131072);

    transpose_feat<<<1024, 256, 0, stream>>>(feat, featT);
    pack_w<<<96,  256, 0, stream>>>(w0, wp0,  68, 256, 3, 16, 1);
    pack_w<<<256, 256, 0, stream>>>(w1, wp1, 256, 256, 8, 16, 1);
    pack_w<<<256, 256, 0, stream>>>(w2, wp2, 256, 256, 8, 16, 1);
    pack_w<<<256, 256, 0, stream>>>(w3, wp3, 256, 256, 8, 16, 1);
    pack_w<<<16,  256, 0, stream>>>(w4, wp4, 256, 3, 8, 1, 0);

    hipFuncSetAttribute(reinterpret_cast<const void*>(mlp_main),
                        hipFuncAttributeMaxDynamicSharedMemorySize, SMEM_BYTES);
    mlp_main<<<4096, THREADS, SMEM_BYTES, stream>>>(
        featT, sgrid, scell, wp0, wp1, wp2, wp3, wp4,
        b0, b1, b2, b3, b4, (float*)d_out);
}

// Round 14
// 414.104 us; speedup vs baseline: 1.7836x; 1.0820x over previous
//
#include <hip/hip_runtime.h>

// ---------------------------------------------------------------------------
// LIIF-style MLP render on MI355X — R14.
//  Arithmetic-intensity move: 512 thr / 8 waves (2 waves/SIMD), ROWS=256,
//  per-wave tile 64x128 (4wm x 2wn), acc[4][8] = 128 AGPR + ~115 arch VGPR
//  (fits 256/wave at 8 waves/CU).  Fragment traffic per MFMA drops 27%
//  (af wn-redundancy halves).  Group-drift sync retained: each SIMD hosts
//  2 waves from DIFFERENT row-groups -> MFMA/writeback overlap.
//  Numerics verbatim R10/R13 (same kp-ascending chains) -> bit-identical.
// ---------------------------------------------------------------------------

typedef _Float16 half8 __attribute__((ext_vector_type(8)));
typedef float f32x4 __attribute__((ext_vector_type(4)));

#define ROWS     256          // rows per block (query-shift pairs)
#define THREADS  512

#define A_BYTES    131072     // 256 rows x 512 B (256 k x fp16)
#define AREA_OFF   131072     // 256 x f32
#define PRED_OFF   132096     // 256 x 4 x f32
#define FLAG_OFF   136192     // 8 x int (4 rflag + 4 wflag)
#define SMEM_BYTES 136224     // 133 KB -> 1 block/CU

static __device__ __forceinline__ unsigned short f2h(float f) {
    union { _Float16 h; unsigned short u; } v;
    v.h = (_Float16)f;   // v_cvt_f16_f32, RNE
    return v.u;
}

// swizzle: XOR 16B-slot index with row&7 (keeps 16B alignment, bijective)
#define SWZ(row, byte) ((byte) ^ (((row) & 7) << 4))

// column permutation: physical MFMA col p -> logical col PI(p).
// p = ct*16 + l15 -> per-64 block: l15*4 + (ct&3)   (bijective)
static __device__ __host__ __forceinline__ int PI(int p) {
    return ((p >> 6) << 6) | ((p & 15) << 2) | ((p >> 4) & 3);
}

// ---------------------------------------------------------------------------
// feat [B][C][H][W] f32  ->  featT [B][H][W][C] fp16  (LDS tile transpose)
// ---------------------------------------------------------------------------
__global__ void transpose_feat(const float* __restrict__ feat,
                               unsigned short* __restrict__ featT) {
    __shared__ float tile[64][65];
    const int bi  = blockIdx.x;          // B*H*2 = 1024 blocks
    const int b   = bi >> 8;
    const int rem = bi & 255;
    const int y   = rem >> 1;
    const int xc  = (rem & 1) << 6;
    const int tid = threadIdx.x;

    {
        const int x  = tid & 63;
        const int cg = tid >> 6;          // 0..3
#pragma unroll
        for (int i = 0; i < 16; ++i) {
            int c = cg * 16 + i;
            tile[c][x] = feat[(((b << 6) + c) << 14) + (y << 7) + xc + x];
        }
    }
    __syncthreads();
    {
        const int c  = tid & 63;
        const int xg = tid >> 6;
#pragma unroll
        for (int i = 0; i < 16; ++i) {
            int xx = xg * 16 + i;
            featT[(size_t)((((b << 7) + y) << 7) + xc + xx) * 64 + c] =
                f2h(tile[c][xx]);
        }
    }
}

// ---------------------------------------------------------------------------
// Pack weight [K][N] f32 -> fragment layout fp16:
//   dst[((ks*nct + ct)*64 + lane)*8 + j] = W[k][n_src],
//   k = ks*32 + (lane>>4)*8 + j, n_phys = ct*16 + (lane&15),
//   n_src = permN ? PI(n_phys) : n_phys.  Zero-padded outside K,N.
// ---------------------------------------------------------------------------
__global__ void pack_w(const float* __restrict__ src,
                       unsigned short* __restrict__ dst,
                       int K, int N, int ksteps, int nct, int permN) {
    int tid = blockIdx.x * 256 + threadIdx.x;
    int total = ksteps * nct * 512;
    if (tid >= total) return;
    int j    = tid & 7;
    int lane = (tid >> 3) & 63;
    int f    = tid >> 9;
    int ct   = f % nct;
    int ks   = f / nct;
    int k = ks * 32 + ((lane >> 4) << 3) + j;
    int n = ct * 16 + (lane & 15);
    int ns = permN ? PI(n) : n;
    float v = (k < K && ns < N) ? src[k * N + ns] : 0.0f;
    dst[tid] = f2h(v);
}

// ---------------------------------------------------------------------------
// One hidden layer: K-panel MFMA loop (64x128 tile) + PI writeback,
// group-scoped sync (groups of 2 waves).
// ---------------------------------------------------------------------------
template <int NP>
static __device__ __forceinline__ void layer_step(
    char* A, int* rflag, int* wflag, int target,
    const unsigned short* __restrict__ wsel,
    const float* __restrict__ bsel,
    int lane, int wm, int wn) {

    const int l15 = lane & 15;
    f32x4 acc[4][8];
#pragma unroll
    for (int rf = 0; rf < 4; ++rf)
#pragma unroll
        for (int cf = 0; cf < 8; ++cf)
            acc[rf][cf] = (f32x4){0.f, 0.f, 0.f, 0.f};

#pragma unroll 2
    for (int kp = 0; kp < NP; ++kp) {
        half8 af[4], bf[8];
        const int kbyte = (kp << 6) + ((lane >> 4) << 4);
        const int xorv  = (lane & 7) << 4;
#pragma unroll
        for (int rf = 0; rf < 4; ++rf) {
            int row = wm * 64 + rf * 16 + l15;
            af[rf] = *(const half8*)(A + row * 512 + (kbyte ^ xorv));
        }
#pragma unroll
        for (int cf = 0; cf < 8; ++cf)
            bf[cf] = *(const half8*)(wsel + (size_t)((kp * 16 + wn * 8 + cf) * 64 + lane) * 8);
        __builtin_amdgcn_s_setprio(1);
#pragma unroll
        for (int rf = 0; rf < 4; ++rf)
#pragma unroll
            for (int cf = 0; cf < 8; ++cf)
                acc[rf][cf] = __builtin_amdgcn_mfma_f32_16x16x32_f16(
                    af[rf], bf[cf], acc[rf][cf], 0, 0, 0);
        __builtin_amdgcn_s_setprio(0);
    }

    // group-scoped "all A reads done" (RELEASE drains lgkmcnt incl. reads)
    if (lane == 0)
        __hip_atomic_fetch_add(rflag, 1, __ATOMIC_RELEASE,
                               __HIP_MEMORY_SCOPE_WORKGROUP);
    while (__hip_atomic_load(rflag, __ATOMIC_ACQUIRE,
                             __HIP_MEMORY_SCOPE_WORKGROUP) < target)
        __builtin_amdgcn_s_sleep(4);

    // bias + relu + PACKED writeback.  PI makes each cf-quad of logical
    // cols contiguous: cf 0..3 -> cols wn*256 + l15*4 + cf (in 64-block
    // wn*2), cf 4..7 -> same + 64 cols (64-block wn*2+1).
    const float4 biasA = *(const float4*)(bsel + wn * 128 + l15 * 4);
    const float4 biasB = *(const float4*)(bsel + wn * 128 + 64 + l15 * 4);
    const int colb0 = (wn << 8) + (l15 << 3);   // logical col * 2B
    const int colb1 = colb0 + 128;

#pragma unroll
    for (int rf = 0; rf < 4; ++rf) {
        const int rbase = wm * 64 + rf * 16 + ((lane >> 4) << 2);
#pragma unroll
        for (int q = 0; q < 4; ++q) {
            const int row = rbase + q;
            const int rx  = (row & 7) << 4;
            union { _Float16 h[4]; uint2 u; } pk;
            pk.h[0] = (_Float16)fmaxf(acc[rf][0][q] + biasA.x, 0.0f);
            pk.h[1] = (_Float16)fmaxf(acc[rf][1][q] + biasA.y, 0.0f);
            pk.h[2] = (_Float16)fmaxf(acc[rf][2][q] + biasA.z, 0.0f);
            pk.h[3] = (_Float16)fmaxf(acc[rf][3][q] + biasA.w, 0.0f);
            *(uint2*)(A + row * 512 + (colb0 ^ rx)) = pk.u;
            pk.h[0] = (_Float16)fmaxf(acc[rf][4][q] + biasB.x, 0.0f);
            pk.h[1] = (_Float16)fmaxf(acc[rf][5][q] + biasB.y, 0.0f);
            pk.h[2] = (_Float16)fmaxf(acc[rf][6][q] + biasB.z, 0.0f);
            pk.h[3] = (_Float16)fmaxf(acc[rf][7][q] + biasB.w, 0.0f);
            *(uint2*)(A + row * 512 + (colb1 ^ rx)) = pk.u;
        }
    }

    // group-scoped "all A writes done" (RELEASE drains the ds_writes)
    if (lane == 0)
        __hip_atomic_fetch_add(wflag, 1, __ATOMIC_RELEASE,
                               __HIP_MEMORY_SCOPE_WORKGROUP);
    while (__hip_atomic_load(wflag, __ATOMIC_ACQUIRE,
                             __HIP_MEMORY_SCOPE_WORKGROUP) < target)
        __builtin_amdgcn_s_sleep(4);
}

// ---------------------------------------------------------------------------
// Main fused kernel
// ---------------------------------------------------------------------------
__global__ __launch_bounds__(512, 2) void mlp_main(
    const unsigned short* __restrict__ featT,
    const float* __restrict__ sgrid,
    const float* __restrict__ scell,
    const unsigned short* __restrict__ wp0, const unsigned short* __restrict__ wp1,
    const unsigned short* __restrict__ wp2, const unsigned short* __restrict__ wp3,
    const unsigned short* __restrict__ wp4,
    const float* __restrict__ bp0, const float* __restrict__ bp1,
    const float* __restrict__ bp2, const float* __restrict__ bp3,
    const float* __restrict__ bp4,
    float* __restrict__ out) {

    extern __shared__ char lds[];
    char*  A     = lds;                          // 256 x 512B fp16 activations
    float* areas = (float*)(lds + AREA_OFF);     // 256 f32
    float* predl = (float*)(lds + PRED_OFF);     // 256 x 4 f32
    int*   flags = (int*)(lds + FLAG_OFF);       // [0..3]=rflag [4..7]=wflag

    const int tid  = threadIdx.x;
    const int lane = tid & 63;
    const int wv   = tid >> 6;     // wave 0..7
    const int wm   = wv >> 1;      // row group (0..3): rows wm*64..+63
    const int wn   = wv & 1;       // col half (0..1): cols wn*128..+127

    if (tid < 8) flags[tid] = 0;

    // ---------------- phase 0: build MLP inputs into A (R4 verbatim) -------
    {
        const int row  = tid >> 1;
        const int half = tid & 1;
        const int grow = blockIdx.x * ROWS + row;
        const int qq   = grow >> 2;        // global query index (b*Q+q)
        const int s    = grow & 3;         // shift: 0:(-,-) 1:(-,+) 2:(+,-) 3:(+,+)
        const int b    = qq >> 16;

        const float g0 = sgrid[qq * 2 + 0];
        const float g1 = sgrid[qq * 2 + 1];
        const float c0 = scell[qq * 2 + 0];
        const float c1 = scell[qq * 2 + 1];

        const float rs = (s & 2) ? 1.0f : -1.0f;
        const float cs = (s & 1) ? 1.0f : -1.0f;
        const float dh = 0.0078125f;                   // 1/128
        const float LO = (float)(-1.0 + 1e-6);
        const float HI = (float)( 1.0 - 1e-6);

        // exact same fp32 op order as reference
        float gy = fminf(fmaxf(g0 + rs * dh, LO), HI);
        float gx = fminf(fmaxf(g1 + cs * dh, LO), HI);
        float ty = ((gy + 1.0f) * 128.0f - 1.0f) * 0.5f;
        float tx = ((gx + 1.0f) * 128.0f - 1.0f) * 0.5f;
        int iy = (int)rintf(ty); iy = min(max(iy, 0), 127);
        int ix = (int)rintf(tx); ix = min(max(ix, 0), 127);

        float py = -1.0f + (float)(2 * iy + 1) * 0.0078125f;
        float px = -1.0f + (float)(2 * ix + 1) * 0.0078125f;
        float rel_y = (g0 - py) * 128.0f;
        float rel_x = (g1 - px) * 128.0f;
        float qcy = c0 * 128.0f;
        float qcx = c1 * 128.0f;

        if (half == 0) areas[row] = fabsf(rel_y * rel_x) + 1e-9f;

        // gather 32 channels (64B) of fp16 features
        const unsigned short* src =
            featT + (size_t)((((b << 7) + iy) << 7) + ix) * 64 + (half << 5);
        uint4 v0 = *(const uint4*)(src + 0);
        uint4 v1 = *(const uint4*)(src + 8);
        uint4 v2 = *(const uint4*)(src + 16);
        uint4 v3 = *(const uint4*)(src + 24);

        char* arow = A + row * 512;
        const int kb0 = half << 6;     // byte offset of k = half*32
        *(uint4*)(arow + SWZ(row, kb0 +  0)) = v0;
        *(uint4*)(arow + SWZ(row, kb0 + 16)) = v1;
        *(uint4*)(arow + SWZ(row, kb0 + 32)) = v2;
        *(uint4*)(arow + SWZ(row, kb0 + 48)) = v3;

        if (half) {    // k = 64..95 : rel_y, rel_x, qcy, qcx, zeros
            uint4 t;
            t.x = (unsigned)f2h(rel_y) | ((unsigned)f2h(rel_x) << 16);
            t.y = (unsigned)f2h(qcy)   | ((unsigned)f2h(qcx)   << 16);
            t.z = 0; t.w = 0;
            uint4 z = {0, 0, 0, 0};
            *(uint4*)(arow + SWZ(row, 128)) = t;
            *(uint4*)(arow + SWZ(row, 144)) = z;
            *(uint4*)(arow + SWZ(row, 160)) = z;
            *(uint4*)(arow + SWZ(row, 176)) = z;
        }
    }
    __syncthreads();   // phase 0 + flag init visible to all (cross-group)

    // ---------------- layers 0..3 (group-scoped sync, 2 waves/group) -------
    int* rflag = &flags[wm];
    int* wflag = &flags[4 + wm];
    layer_step<3>(A, rflag, wflag, 2, wp0, bp0, lane, wm, wn);
    layer_step<8>(A, rflag, wflag, 4, wp1, bp1, lane, wm, wn);
    layer_step<8>(A, rflag, wflag, 6, wp2, bp2, lane, wm, wn);
    layer_step<8>(A, rflag, wflag, 8, wp3, bp3, lane, wm, wn);

    // ---------------- layer 4 (256 -> 3, N padded to 16) -------------------
    // wave wv reads rows wv*32..+31, all inside its own group wm=wv>>1,
    // whose final writes are guaranteed by the last wflag spin above.
    {
        f32x4 a4[2];
        a4[0] = (f32x4){0.f, 0.f, 0.f, 0.f};
        a4[1] = (f32x4){0.f, 0.f, 0.f, 0.f};
        const int xorv = (lane & 7) << 4;
#pragma unroll
        for (int kp = 0; kp < 8; ++kp) {
            const int kbyte = (kp << 6) + ((lane >> 4) << 4);
            half8 b = *(const half8*)(wp4 + (size_t)((kp * 64) + lane) * 8);
#pragma unroll
            for (int rr = 0; rr < 2; ++rr) {
                int row = wv * 32 + rr * 16 + (lane & 15);
                half8 a = *(const half8*)(A + row * 512 + (kbyte ^ xorv));
                a4[rr] = __builtin_amdgcn_mfma_f32_16x16x32_f16(a, b, a4[rr], 0, 0, 0);
            }
        }

        const int col = lane & 15;
        const float b4v = (col < 3) ? bp4[col] : 0.0f;
        if (col < 3) {
#pragma unroll
            for (int rr = 0; rr < 2; ++rr)
#pragma unroll
                for (int q = 0; q < 4; ++q) {
                    int row = wv * 32 + rr * 16 + ((lane >> 4) << 2) + q;
                    predl[row * 4 + col] = a4[rr][q] + b4v;
                }
        }
        __syncthreads();   // predl is read cross-group below

        // combine 4 shifts with diagonally swapped areas (R4 verbatim)
        if (tid < 192) {
            int qloc = tid / 3;
            int c    = tid - qloc * 3;
            int r0   = qloc * 4;
            float a0 = areas[r0 + 0], a1 = areas[r0 + 1];
            float a2 = areas[r0 + 2], a3 = areas[r0 + 3];
            float total = ((a0 + a1) + a2) + a3;
            float ret = predl[(r0 + 0) * 4 + c] * (a3 / total);
            ret      += predl[(r0 + 1) * 4 + c] * (a2 / total);
            ret      += predl[(r0 + 2) * 4 + c] * (a1 / total);
            ret      += predl[(r0 + 3) * 4 + c] * (a0 / total);
            int qq0 = blockIdx.x * 64 + qloc;
            out[qq0 * 3 + c] = ret;
        }
    }
}

// ---------------------------------------------------------------------------
extern "C" void kernel_launch(void* const* d_in, const int* in_sizes, int n_in,
                              void* d_out, int out_size, void* d_ws, size_t ws_size,
                              hipStream_t stream) {
    const float* feat  = (const float*)d_in[0];
    const float* sgrid = (const float*)d_in[1];
    const float* scell = (const float*)d_in[2];
    const float* w0 = (const float*)d_in[3];
    const float* b0 = (const float*)d_in[4];
    const float* w1 = (const float*)d_in[5];
    const float* b1 = (const float*)d_in[6];
    const float* w2 = (const float*)d_in[7];
    const float* b2 = (const float*)d_in[8];
    const float* w3 = (const float*)d_in[9];
    const float* b3 = (const float*)d_in[10];
    const float* w4 = (const float*)d_in[11];
    const float* b4 = (const float*)d_in[12];

    char* ws = (char*)d_ws;
    unsigned short* featT = (unsigned short*)ws;
    unsigned short* wp0 = (unsigned short*)(ws + 8388608);
    unsigned short* wp1 = (unsigned short*)(ws + 8388608 + 49152);
    unsigned short* wp2 = (unsigned short*)(ws + 8388608 + 49152 + 131072);
    unsigned short* wp3 = (unsigned short*)(ws + 8388608 + 49152 + 2 * 131072);
    unsigned short* wp4 = (unsigned short*)(ws + 8388608 + 49152 + 3 * 131072);

    transpose_feat<<<1024, 256, 0, stream>>>(feat, featT);
    pack_w<<<96,  256, 0, stream>>>(w0, wp0,  68, 256, 3, 16, 1);
    pack_w<<<256, 256, 0, stream>>>(w1, wp1, 256, 256, 8, 16, 1);
    pack_w<<<256, 256, 0, stream>>>(w2, wp2, 256, 256, 8, 16, 1);
    pack_w<<<256, 256, 0, stream>>>(w3, wp3, 256, 256, 8, 16, 1);
    pack_w<<<16,  256, 0, stream>>>(w4, wp4, 256, 3, 8, 1, 0);

    hipFuncSetAttribute(reinterpret_cast<const void*>(mlp_main),
                        hipFuncAttributeMaxDynamicSharedMemorySize, SMEM_BYTES);
    mlp_main<<<4096, THREADS, SMEM_BYTES, stream>>>(
        featT, sgrid, scell, wp0, wp1, wp2, wp3, wp4,
        b0, b1, b2, b3, b4, (float*)d_out);
}